// Round 3
// baseline (59.253 us; speedup 1.0000x reference)
//
#include <hip/hip_runtime.h>

// ALS gather-dot: out[b] = dot(user[loc[b,0], :], goods[:, loc[b,1]])
// user: [500000, 128] f32 row-major   -> row gather, contiguous (512 B/row)
// goods: [128, 500000] f32 row-major  -> column gather, stride 2 MB (scattered 4 B)
// location: [16384, 2] int            -> out: [16384] f32
//
// R2: counting-sort batch items by goods-column 128B-line bucket (gcol>>5),
// then gather in sorted order with XCD-chunked block swizzle.
//  - ~38% line dedup (16384 fetches -> ~10160 distinct lines per goods row),
//    captured in L1/L2 because same-line items now share a block.
//  - per-XCD near-sequential line sweep per goods row -> DRAM-friendly.

#define KDIM 128
#define GOODS_NUM 500000
#define NBUCKET 15625          // 500000 / 32 cols per 128B line
#define OPW 4                  // outputs per wave in gather kernel

// ---------------- Kernel A: counting sort by gcol>>5 ----------------
__global__ __launch_bounds__(1024) void als_bucket_sort(
    const int* __restrict__ loc, int* __restrict__ perm, int batch)
{
    __shared__ int hist[NBUCKET];   // 62.5 KB
    __shared__ int wsum[16];
    const int t = threadIdx.x;
    const int lane = t & 63, wid = t >> 6;

    for (int i = t; i < NBUCKET; i += 1024) hist[i] = 0;
    __syncthreads();

    // histogram
    for (int i = t; i < batch; i += 1024)
        atomicAdd(&hist[loc[2 * i + 1] >> 5], 1);
    __syncthreads();

    // exclusive scan over hist (chunk-per-thread + wave shfl scan)
    const int CH = 16;                 // 1024*16 = 16384 >= 15625
    int local_excl[CH];
    int sum = 0;
    const int base = t * CH;
    #pragma unroll
    for (int c = 0; c < CH; ++c) {
        int idx = base + c;
        int v = (idx < NBUCKET) ? hist[idx] : 0;
        local_excl[c] = sum;
        sum += v;
    }
    int x = sum;                       // inclusive scan of chunk sums within wave
    #pragma unroll
    for (int off = 1; off < 64; off <<= 1) {
        int y = __shfl_up(x, off, 64);
        if (lane >= off) x += y;
    }
    if (lane == 63) wsum[wid] = x;
    __syncthreads();
    int woff = 0;
    for (int w = 0; w < wid; ++w) woff += wsum[w];
    const int chunk_excl = woff + x - sum;
    #pragma unroll
    for (int c = 0; c < CH; ++c) {
        int idx = base + c;
        if (idx < NBUCKET) hist[idx] = chunk_excl + local_excl[c];
    }
    __syncthreads();

    // scatter (within-bucket order nondeterministic; output is order-invariant)
    for (int i = t; i < batch; i += 1024) {
        int b = loc[2 * i + 1] >> 5;
        int pos = atomicAdd(&hist[b], 1);
        perm[pos] = i;
    }
}

// ---------------- Kernel B: gather-dot through perm ----------------
__global__ __launch_bounds__(256) void als_gather_dot_perm(
    const float* __restrict__ user,
    const float* __restrict__ goods,
    const int* __restrict__ loc,
    const int* __restrict__ perm,
    float* __restrict__ out,
    int batch, int chunk_per_xcd)
{
    int h = blockIdx.x;
    // bijective XCD swizzle (grid % 8 == 0): HW round-robins consecutive ids
    // across XCDs; give each XCD a contiguous chunk of the sorted range.
    int swz = (chunk_per_xcd > 0) ? (h & 7) * chunk_per_xcd + (h >> 3) : h;
    const int wave = swz * (256 / 64) + (threadIdx.x >> 6);
    const int lane = threadIdx.x & 63;
    const int base = wave * OPW;
    if (base >= batch) return;

    const int r = lane * 2;

    float2 uv[OPW];
    float g0[OPW], g1[OPW];
    int bidx[OPW];
    #pragma unroll
    for (int j = 0; j < OPW; ++j) {
        const int b = perm[base + j];
        bidx[j] = b;
        const int urow = loc[2 * b + 0];
        const int gcol = loc[2 * b + 1];
        uv[j] = *reinterpret_cast<const float2*>(
            user + (size_t)urow * KDIM + (size_t)r);
        g0[j] = goods[(size_t)r       * GOODS_NUM + (size_t)gcol];
        g1[j] = goods[(size_t)(r + 1) * GOODS_NUM + (size_t)gcol];
    }

    #pragma unroll
    for (int j = 0; j < OPW; ++j) {
        float s = uv[j].x * g0[j] + uv[j].y * g1[j];
        #pragma unroll
        for (int off = 32; off >= 1; off >>= 1)
            s += __shfl_xor(s, off, 64);
        if (lane == 0) out[bidx[j]] = s;
    }
}

extern "C" void kernel_launch(void* const* d_in, const int* in_sizes, int n_in,
                              void* d_out, int out_size, void* d_ws, size_t ws_size,
                              hipStream_t stream)
{
    const float* user  = (const float*)d_in[0];
    const float* goods = (const float*)d_in[1];
    const int*   loc   = (const int*)d_in[2];
    float* out = (float*)d_out;
    int*   perm = (int*)d_ws;                   // 16384 ints

    const int batch = out_size;                 // 16384

    als_bucket_sort<<<1, 1024, 0, stream>>>(loc, perm, batch);

    const int waves = (batch + OPW - 1) / OPW;          // 4096
    const int blocks = (waves * 64 + 255) / 256;        // 1024
    const int chunk = (blocks % 8 == 0) ? blocks / 8 : 0;
    als_gather_dot_perm<<<blocks, 256, 0, stream>>>(
        user, goods, loc, perm, out, batch, chunk);
}